// Round 1
// baseline (109.087 us; speedup 1.0000x reference)
//
#include <hip/hip_runtime.h>
#include <cmath>

#define NB 8
#define DIM 4096
#define NHQ 32
#define NHKV 8
#define NDH 128
#define MAXSEQ 4096
#define STARTPOS 4095
#define QKV_COLS 6144   // 4096 q + 1024 k + 1024 v
#define RCHUNK 64       // rows per split-K chunk
#define NRC 64          // 4096 / 64
#define SCALE 0.08838834764831845f  // 1/sqrt(128)

// ---------------------------------------------------------------------------
// Kernel 1: QKV projection partials.  grid = 12 col-tiles * 64 row-chunks.
// Each thread owns 2 consecutive output columns, accumulates 8 batches.
// part[rc][b][col6144]
__global__ __launch_bounds__(256) void qkv_partial_k(
    const float* __restrict__ x, const float* __restrict__ wq,
    const float* __restrict__ wk, const float* __restrict__ wv,
    float* __restrict__ part) {
  int bid = blockIdx.x;
  int ct = bid % 12, rc = bid / 12;
  int tid = threadIdx.x;
  const float* W; int ldw; int colbase;
  int gcolbase = ct * 512;
  if (ct < 8)       { W = wq; ldw = NHQ * NDH;  colbase = gcolbase; }
  else if (ct < 10) { W = wk; ldw = NHKV * NDH; colbase = gcolbase - 4096; }
  else              { W = wv; ldw = NHKV * NDH; colbase = gcolbase - 5120; }

  __shared__ __align__(16) float xs[RCHUNK][8];
  int rbase = rc * RCHUNK;
  for (int i = tid; i < RCHUNK * 8; i += 256) {
    int b = i >> 6, r = i & 63;
    xs[r][b] = x[b * DIM + rbase + r];
  }
  __syncthreads();

  int col = colbase + tid * 2;
  const float* wp = W + (size_t)rbase * ldw + col;
  float2 acc[8];
#pragma unroll
  for (int b = 0; b < 8; b++) { acc[b].x = 0.f; acc[b].y = 0.f; }

#pragma unroll 8
  for (int r = 0; r < RCHUNK; r++) {
    float2 w2 = *(const float2*)wp; wp += ldw;
    float4 xa = *(const float4*)&xs[r][0];
    float4 xb = *(const float4*)&xs[r][4];
    acc[0].x += xa.x * w2.x; acc[0].y += xa.x * w2.y;
    acc[1].x += xa.y * w2.x; acc[1].y += xa.y * w2.y;
    acc[2].x += xa.z * w2.x; acc[2].y += xa.z * w2.y;
    acc[3].x += xa.w * w2.x; acc[3].y += xa.w * w2.y;
    acc[4].x += xb.x * w2.x; acc[4].y += xb.x * w2.y;
    acc[5].x += xb.y * w2.x; acc[5].y += xb.y * w2.y;
    acc[6].x += xb.z * w2.x; acc[6].y += xb.z * w2.y;
    acc[7].x += xb.w * w2.x; acc[7].y += xb.w * w2.y;
  }
  int gcol = gcolbase + tid * 2;
#pragma unroll
  for (int b = 0; b < 8; b++)
    *(float2*)&part[((size_t)rc * 8 + b) * QKV_COLS + gcol] = acc[b];
}

// ---------------------------------------------------------------------------
// Kernel 2: reduce partials + bias + RoPE (pos = STARTPOS).  49152 threads.
__global__ __launch_bounds__(256) void qkv_reduce_rope_k(
    const float* __restrict__ part, const float* __restrict__ bq,
    const float* __restrict__ bk, const float* __restrict__ bv,
    float* __restrict__ qws, float* __restrict__ kws, float* __restrict__ vws) {
  int idx = blockIdx.x * 256 + threadIdx.x;
  int b = idx / QKV_COLS, col = idx % QKV_COLS;
  float s = 0.f;
#pragma unroll 8
  for (int rcc = 0; rcc < NRC; rcc++)
    s += part[((size_t)rcc * 8 + b) * QKV_COLS + col];
  float bias = (col < 4096) ? bq[col] : (col < 5120 ? bk[col - 4096] : bv[col - 5120]);
  s += bias;
  float outv = s;
  if (col < 5120) {  // q or k -> RoPE
    int dim = col & 127;
    int i2 = dim & ~1;
    float theta = powf(10000.f, -(float)i2 * (1.f / 128.f));
    float ang = (float)STARTPOS * theta;
    float c = cosf(ang), sn = sinf(ang);
    float other = __shfl_xor(s, 1);
    if ((col & 1) == 0) outv = s * c - other * sn;   // xr*cos - xi*sin
    else                outv = other * sn + s * c;   // xr*sin + xi*cos
  }
  if (col < 4096)       qws[b * 4096 + col] = outv;
  else if (col < 5120)  kws[b * 1024 + (col - 4096)] = outv;
  else                  vws[b * 1024 + (col - 5120)] = outv;
}

// ---------------------------------------------------------------------------
// Kernel 3: flash-decoding partials. grid = 64 groups * 16 chunks of 256 pos.
// Block 256 thr. Per block: 4 q-heads of one (b,hkv), chunk of 256 kv pos.
__global__ __launch_bounds__(256) void attn_partial_k(
    const float* __restrict__ q, const float* __restrict__ kws,
    const float* __restrict__ vws, const float* __restrict__ ck,
    const float* __restrict__ cv, float* __restrict__ pm,
    float* __restrict__ pl, float* __restrict__ pacc) {
  int bid = blockIdx.x;
  int chunk = bid & 15, grp = bid >> 4;
  int b = grp >> 3, hkv = grp & 7;
  int tid = threadIdx.x;

  __shared__ __align__(16) float kbuf[64][132];
  __shared__ float sbuf[4][256];
  __shared__ __align__(16) float qbuf[4][132];

  for (int i = tid; i < 512; i += 256) {
    int r = i >> 7, d = i & 127;
    qbuf[r][d] = q[b * 4096 + (hkv * 4 + r) * NDH + d];
  }
  __syncthreads();

  int tchunk = chunk * 256;
  int tl_c = tid >> 2;  // local position 0..63
  int hh = tid & 3;     // head 0..3

  // ---- Phase 1: scores ----
  for (int tile = 0; tile < 4; tile++) {
    int tbase = tchunk + tile * 64;
#pragma unroll
    for (int i = tid; i < 64 * 32; i += 256) {
      int row = i >> 5, c4 = i & 31;
      int t = tbase + row;
      const float* src = (t == STARTPOS)
          ? (kws + ((size_t)b * NHKV + hkv) * NDH)
          : (ck + (((size_t)b * MAXSEQ + t) * NHKV + hkv) * NDH);
      *(float4*)&kbuf[row][c4 * 4] = *(const float4*)(src + c4 * 4);
    }
    __syncthreads();
    float s0 = 0.f, s1 = 0.f;
    const float4* krow = (const float4*)&kbuf[tl_c][0];
    const float4* qrow = (const float4*)&qbuf[hh][0];
#pragma unroll
    for (int c = 0; c < 32; c += 2) {
      float4 kv = krow[c];     float4 qv = qrow[c];
      s0 += kv.x * qv.x + kv.y * qv.y + kv.z * qv.z + kv.w * qv.w;
      float4 kv2 = krow[c + 1]; float4 qv2 = qrow[c + 1];
      s1 += kv2.x * qv2.x + kv2.y * qv2.y + kv2.z * qv2.z + kv2.w * qv2.w;
    }
    sbuf[hh][tile * 64 + tl_c] = (s0 + s1) * SCALE;
    __syncthreads();
  }

  // ---- Phase 2: per-head softmax over the 256-pos chunk (wave = head) ----
  int wv_ = tid >> 6;
  int lane = tid & 63;
  float e0 = sbuf[wv_][lane];
  float e1 = sbuf[wv_][lane + 64];
  float e2 = sbuf[wv_][lane + 128];
  float e3 = sbuf[wv_][lane + 192];
  float m = fmaxf(fmaxf(e0, e1), fmaxf(e2, e3));
#pragma unroll
  for (int off = 32; off; off >>= 1) m = fmaxf(m, __shfl_xor(m, off));
  float p0 = expf(e0 - m), p1 = expf(e1 - m), p2 = expf(e2 - m), p3 = expf(e3 - m);
  float l = p0 + p1 + p2 + p3;
#pragma unroll
  for (int off = 32; off; off >>= 1) l += __shfl_xor(l, off);
  sbuf[wv_][lane] = p0;
  sbuf[wv_][lane + 64] = p1;
  sbuf[wv_][lane + 128] = p2;
  sbuf[wv_][lane + 192] = p3;
  if (lane == 0) {
    pm[((size_t)grp * 16 + chunk) * 4 + wv_] = m;
    pl[((size_t)grp * 16 + chunk) * 4 + wv_] = l;
  }
  __syncthreads();

  // ---- Phase 3: V accumulation (wave = head, lane = 2 dims) ----
  float2 acc2 = {0.f, 0.f};
  int d0 = lane * 2;
  for (int tile = 0; tile < 4; tile++) {
    int tbase = tchunk + tile * 64;
#pragma unroll
    for (int i = tid; i < 64 * 32; i += 256) {
      int row = i >> 5, c4 = i & 31;
      int t = tbase + row;
      const float* src = (t == STARTPOS)
          ? (vws + ((size_t)b * NHKV + hkv) * NDH)
          : (cv + (((size_t)b * MAXSEQ + t) * NHKV + hkv) * NDH);
      *(float4*)&kbuf[row][c4 * 4] = *(const float4*)(src + c4 * 4);
    }
    __syncthreads();
#pragma unroll 8
    for (int tl = 0; tl < 64; tl++) {
      float p = sbuf[wv_][tile * 64 + tl];
      float2 v2 = *(const float2*)&kbuf[tl][d0];
      acc2.x += p * v2.x;
      acc2.y += p * v2.y;
    }
    __syncthreads();
  }
  *(float2*)&pacc[(((size_t)grp * 16 + chunk) * 4 + wv_) * NDH + d0] = acc2;
}

// ---------------------------------------------------------------------------
// Kernel 4: combine 16 chunk partials per (b,hq).  grid 256, block 128.
__global__ __launch_bounds__(128) void attn_combine_k(
    const float* __restrict__ pm, const float* __restrict__ pl,
    const float* __restrict__ pacc, float* __restrict__ aout) {
  int bid = blockIdx.x;
  int b = bid >> 5, hq = bid & 31;
  int grp = b * 8 + (hq >> 2), r = hq & 3;
  int d = threadIdx.x;
  float mv[16];
  float M = -1e30f;
#pragma unroll
  for (int c = 0; c < 16; c++) {
    mv[c] = pm[((size_t)grp * 16 + c) * 4 + r];
    M = fmaxf(M, mv[c]);
  }
  float L = 0.f;
  float w[16];
#pragma unroll
  for (int c = 0; c < 16; c++) {
    w[c] = expf(mv[c] - M);
    L += w[c] * pl[((size_t)grp * 16 + c) * 4 + r];
  }
  float o = 0.f;
#pragma unroll
  for (int c = 0; c < 16; c++)
    o += w[c] * pacc[(((size_t)grp * 16 + c) * 4 + r) * NDH + d];
  aout[(size_t)b * 4096 + hq * NDH + d] = o / L;
}

// ---------------------------------------------------------------------------
// Kernel 5: output projection partials. grid = 8 col-tiles * 64 row-chunks.
__global__ __launch_bounds__(256) void out_partial_k(
    const float* __restrict__ ain, const float* __restrict__ wo,
    float* __restrict__ part) {
  int bid = blockIdx.x;
  int ct = bid & 7, rc = bid >> 3;
  int tid = threadIdx.x;
  __shared__ __align__(16) float xs[RCHUNK][8];
  int rbase = rc * RCHUNK;
  for (int i = tid; i < RCHUNK * 8; i += 256) {
    int b = i >> 6, r = i & 63;
    xs[r][b] = ain[(size_t)b * 4096 + rbase + r];
  }
  __syncthreads();

  int col = ct * 512 + tid * 2;
  const float* wp = wo + (size_t)rbase * 4096 + col;
  float2 acc[8];
#pragma unroll
  for (int b = 0; b < 8; b++) { acc[b].x = 0.f; acc[b].y = 0.f; }
#pragma unroll 8
  for (int r = 0; r < RCHUNK; r++) {
    float2 w2 = *(const float2*)wp; wp += 4096;
    float4 xa = *(const float4*)&xs[r][0];
    float4 xb = *(const float4*)&xs[r][4];
    acc[0].x += xa.x * w2.x; acc[0].y += xa.x * w2.y;
    acc[1].x += xa.y * w2.x; acc[1].y += xa.y * w2.y;
    acc[2].x += xa.z * w2.x; acc[2].y += xa.z * w2.y;
    acc[3].x += xa.w * w2.x; acc[3].y += xa.w * w2.y;
    acc[4].x += xb.x * w2.x; acc[4].y += xb.x * w2.y;
    acc[5].x += xb.y * w2.x; acc[5].y += xb.y * w2.y;
    acc[6].x += xb.z * w2.x; acc[6].y += xb.z * w2.y;
    acc[7].x += xb.w * w2.x; acc[7].y += xb.w * w2.y;
  }
#pragma unroll
  for (int b = 0; b < 8; b++)
    *(float2*)&part[((size_t)rc * 8 + b) * 4096 + col] = acc[b];
}

// ---------------------------------------------------------------------------
// Kernel 6: reduce wo partials + bias -> d_out.  32768 threads.
__global__ __launch_bounds__(256) void out_reduce_k(
    const float* __restrict__ part, const float* __restrict__ bo,
    float* __restrict__ out) {
  int idx = blockIdx.x * 256 + threadIdx.x;
  int b = idx >> 12, col = idx & 4095;
  float s = bo[col];
#pragma unroll 8
  for (int rcc = 0; rcc < NRC; rcc++)
    s += part[((size_t)rcc * 8 + b) * 4096 + col];
  out[idx] = s;
  (void)b;
}

// ---------------------------------------------------------------------------
extern "C" void kernel_launch(void* const* d_in, const int* in_sizes, int n_in,
                              void* d_out, int out_size, void* d_ws, size_t ws_size,
                              hipStream_t stream) {
  const float* x       = (const float*)d_in[0];
  const float* wq      = (const float*)d_in[1];
  const float* bq      = (const float*)d_in[2];
  const float* wk      = (const float*)d_in[3];
  const float* bk      = (const float*)d_in[4];
  const float* wv      = (const float*)d_in[5];
  const float* bv      = (const float*)d_in[6];
  const float* wo      = (const float*)d_in[7];
  const float* bo      = (const float*)d_in[8];
  const float* cache_k = (const float*)d_in[9];
  const float* cache_v = (const float*)d_in[10];
  float* out = (float*)d_out;

  float* ws = (float*)d_ws;
  float* qkv_part = ws;                       // 64*8*6144 = 3,145,728 floats
  float* wo_part  = ws;                       // alias (2,097,152) — reused after qkv consumed
  float* qws  = ws + 3145728;                 // 32768
  float* kws  = qws + 32768;                  // 8192
  float* vws  = kws + 8192;                   // 8192
  float* pm   = vws + 8192;                   // 4096
  float* pl   = pm + 4096;                    // 4096
  float* pacc = pl + 4096;                    // 524288
  float* aout = pacc + 524288;                // 32768
  // total ~15.1 MB

  qkv_partial_k<<<768, 256, 0, stream>>>(x, wq, wk, wv, qkv_part);
  qkv_reduce_rope_k<<<192, 256, 0, stream>>>(qkv_part, bq, bk, bv, qws, kws, vws);
  attn_partial_k<<<1024, 256, 0, stream>>>(qws, kws, vws, cache_k, cache_v, pm, pl, pacc);
  attn_combine_k<<<256, 128, 0, stream>>>(pm, pl, pacc, aout);
  out_partial_k<<<512, 256, 0, stream>>>(aout, wo, wo_part);
  out_reduce_k<<<128, 256, 0, stream>>>(wo_part, bo, out);
}